// Round 7
// baseline (76.245 us; speedup 1.0000x reference)
//
#include <hip/hip_runtime.h>
#include <math.h>

// Fixed shapes: b_edges (64,1,512,512) f32, sobel (64,2,512,512) f32
// BASE=256, PY_SIZES=[256,64]
// Group g = b*64 + R owns output rows 4R..4R+3 (input rows 8R..8R+7).
// prepE: one wave per group; lane X owns cols 4X..4X+3 == one level-1 cell.
// prepSa: one wave per (group, y-half) — 8192 waves for latency hiding.
// 512->256 align-corners: pos(i)=i*511/255 (exact f32 product, IEEE div),
// lo(i)=2i, w=pos-2i (i=255 -> w=1.0, bit-identical to the lo=hi=511 form).

typedef unsigned long long u64;
#define OFFSET1 4194304   // lin_id offset of level 1 (=64*256*256)

// ---------------------------------------------------------------------------
// prepE: E-only pass. 16 upfront float4 loads per lane (rows 8R..8R+7, cols
// 8X..8X+7), predicates for the lane's 16 pixels, ballots -> counts + masks.
// ---------------------------------------------------------------------------
__global__ __launch_bounds__(256) void prepE_kernel(const float* __restrict__ E,
                                                    unsigned short* __restrict__ pred16,
                                                    u64* __restrict__ mask1,
                                                    int* __restrict__ counts0,
                                                    int* __restrict__ counts1) {
    int lane = threadIdx.x & 63;
    int g = blockIdx.x * 4 + (threadIdx.x >> 6);     // 0..4095
    int b = g >> 6, R = g & 63;

    const float* Ep = E + b * 262144 + (8 * R) * 512 + 8 * lane;
    float4 L[8], H[8];
    #pragma unroll
    for (int k = 0; k < 8; ++k) {
        L[k] = *(const float4*)(Ep + k * 512);
        H[k] = *(const float4*)(Ep + k * 512 + 4);
    }

    float wx[4], cwx[4];
    #pragma unroll
    for (int j = 0; j < 4; ++j) {
        int xi = 4 * lane + j;
        wx[j] = (float)(xi * 511) / 255.0f - (float)(8 * lane + 2 * j);
        cwx[j] = 1.0f - wx[j];
    }

    unsigned pred = 0;
    int rc = 0;
    #pragma unroll
    for (int r = 0; r < 4; ++r) {
        int y = 4 * R + r;
        float wy = (float)(y * 511) / 255.0f - (float)(2 * y);
        float cwy = 1.0f - wy;
        float4 lo = L[2 * r], loh = H[2 * r];
        float4 hi = L[2 * r + 1], hih = H[2 * r + 1];
        float e0 = (lo.x*cwy + hi.x*wy)*cwx[0] + (lo.y*cwy + hi.y*wy)*wx[0];
        float e1 = (lo.z*cwy + hi.z*wy)*cwx[1] + (lo.w*cwy + hi.w*wy)*wx[1];
        float e2 = (loh.x*cwy + hih.x*wy)*cwx[2] + (loh.y*cwy + hih.y*wy)*wx[2];
        float e3 = (loh.z*cwy + hih.z*wy)*cwx[3] + (loh.w*cwy + hih.w*wy)*wx[3];
        bool p0 = (e0 != 0.0f), p1 = (e1 != 0.0f), p2 = (e2 != 0.0f), p3 = (e3 != 0.0f);
        pred |= (p0?1u:0u) << (4*r+0);
        pred |= (p1?1u:0u) << (4*r+1);
        pred |= (p2?1u:0u) << (4*r+2);
        pred |= (p3?1u:0u) << (4*r+3);
        u64 b0 = __ballot(p0), b1 = __ballot(p1), b2 = __ballot(p2), b3 = __ballot(p3);
        rc += __popcll(b0) + __popcll(b1) + __popcll(b2) + __popcll(b3);
    }
    u64 m1 = __ballot(pred != 0);
    pred16[g * 64 + lane] = (unsigned short)pred;
    if (lane == 0) {
        counts0[g] = rc;
        counts1[g] = __popcll(m1);
        mask1[g] = m1;
    }
}

// single-block exclusive scan of counts0[4096] and counts1[4096]
__global__ __launch_bounds__(1024) void scan_kernel(const int* __restrict__ counts0,
                                                    int* __restrict__ offs0,
                                                    const int* __restrict__ counts1,
                                                    int* __restrict__ offs1,
                                                    int* __restrict__ totals) {
    __shared__ int wsum[16];
    int tid = threadIdx.x, lane = tid & 63, wave = tid >> 6;

    int carry = 0;
    for (int base = 0; base < 4096; base += 1024) {
        int v = counts0[base + tid];
        int inc = v;
        #pragma unroll
        for (int d = 1; d < 64; d <<= 1) {
            int t = __shfl_up(inc, (unsigned)d, 64);
            if (lane >= d) inc += t;
        }
        if (lane == 63) wsum[wave] = inc;
        __syncthreads();
        int wbase = 0;
        for (int i = 0; i < wave; ++i) wbase += wsum[i];
        int tot = 0;
        #pragma unroll
        for (int i = 0; i < 16; ++i) tot += wsum[i];
        offs0[base + tid] = carry + wbase + inc - v;
        carry += tot;
        __syncthreads();
    }
    if (tid == 0) totals[0] = carry;

    int carry1 = 0;
    for (int base = 0; base < 4096; base += 1024) {
        int v = counts1[base + tid];
        int inc = v;
        #pragma unroll
        for (int d = 1; d < 64; d <<= 1) {
            int t = __shfl_up(inc, (unsigned)d, 64);
            if (lane >= d) inc += t;
        }
        if (lane == 63) wsum[wave] = inc;
        __syncthreads();
        int wbase = 0;
        for (int i = 0; i < wave; ++i) wbase += wsum[i];
        int tot = 0;
        #pragma unroll
        for (int i = 0; i < 16; ++i) tot += wsum[i];
        offs1[base + tid] = carry1 + wbase + inc - v;
        carry1 += tot;
        __syncthreads();
    }
    if (tid == 0) totals[1] = carry1;
}

__device__ __forceinline__ void write_row(float* __restrict__ out, int N, int row,
                                          float cy, float cx, float s0v, float s1v,
                                          float half, float sz, float imgid,
                                          float prow, float mylin) {
    float len = sqrtf(s0v * s0v + s1v * s1v);
    float n0 = s0v / len, n1 = s1v / len;
    float rt0 = n1 * half, rt1 = -n0 * half;
    ((float2*)out)[row]           = make_float2(cy + rt0, cx + rt1);  // locs_lf
    ((float2*)(out + 2 * N))[row] = make_float2(cy - rt0, cx - rt1);  // locs_rt
    ((float2*)(out + 4 * N))[row] = make_float2(n0, n1);              // norms
    out[6 * N + row] = sz;                                            // sizes
    ((float2*)(out + 7 * N))[row] = make_float2(cy, cx);              // centers
    out[9 * N + row] = imgid;                                         // imgid
    out[10 * N + row] = prow;                                         // p_rowids
    out[11 * N + row] = mylin;                                        // my_lin
}

// ---------------------------------------------------------------------------
// prepSa: S pass + level-0 output writes. Wave = (group, y-half): 2 output
// rows, 16 float4 loads/lane. Earlier-half rank recomputed from pred16 via
// ballots. Writes float2 partial 4x2 sobel sums for the L1 pool.
// ---------------------------------------------------------------------------
__global__ __launch_bounds__(256) void prepSa_kernel(const float* __restrict__ S,
                                                     const unsigned short* __restrict__ pred16,
                                                     const u64* __restrict__ mask1,
                                                     const int* __restrict__ offs0,
                                                     const int* __restrict__ offs1,
                                                     const int* __restrict__ totals,
                                                     float2* __restrict__ part,
                                                     float* __restrict__ out, int N) {
    int tid = threadIdx.x;
    int lane = tid & 63;
    int gh = blockIdx.x * 4 + (tid >> 6);            // 0..8191
    int g = gh >> 1, h = gh & 1;
    int bimg = g >> 6, R = g & 63;

    unsigned pred = pred16[g * 64 + lane];
    u64 m1 = mask1[g];
    int base0 = offs0[g];
    int prow = totals[0] + offs1[g] + __popcll(m1 & ((1ull << lane) - 1ull));

    float wx[4], cwx[4];
    #pragma unroll
    for (int j = 0; j < 4; ++j) {
        int xi = 4 * lane + j;
        wx[j] = (float)(xi * 511) / 255.0f - (float)(8 * lane + 2 * j);
        cwx[j] = 1.0f - wx[j];
    }

    // input rows 8R+4h .. +3, cols 8*lane .. +7, both channels
    const float* Sa = S + (size_t)(2 * bimg) * 262144 + (8 * R + 4 * h) * 512 + 8 * lane;
    const float* Sq = Sa + 262144;
    float4 A[4], Ax[4], Q[4], Qx[4];
    #pragma unroll
    for (int k = 0; k < 4; ++k) {
        A[k]  = *(const float4*)(Sa + k * 512);
        Ax[k] = *(const float4*)(Sa + k * 512 + 4);
        Q[k]  = *(const float4*)(Sq + k * 512);
        Qx[k] = *(const float4*)(Sq + k * 512 + 4);
    }

    // actives in earlier half's rows (h==1 -> rows 0,1) — wave-uniform h
    int rc = 0;
    if (h) {
        #pragma unroll
        for (int r = 0; r < 2; ++r) {
            unsigned pr = (pred >> (4 * r)) & 0xF;
            rc += __popcll(__ballot((pr & 1) != 0)) + __popcll(__ballot((pr & 2) != 0)) +
                  __popcll(__ballot((pr & 4) != 0)) + __popcll(__ballot((pr & 8) != 0));
        }
    }

    float acc0 = 0.0f, acc1 = 0.0f;
    #pragma unroll
    for (int rr = 0; rr < 2; ++rr) {
        int r = 2 * h + rr;
        int y = 4 * R + r;
        float wy = (float)(y * 511) / 255.0f - (float)(2 * y);
        float cwy = 1.0f - wy;
        float4 lo = A[2*rr], loh = Ax[2*rr], hi = A[2*rr+1], hih = Ax[2*rr+1];
        float4 ql = Q[2*rr], qlh = Qx[2*rr], qh = Q[2*rr+1], qhh = Qx[2*rr+1];
        float va[4], vb[4];
        va[0] = (lo.x*cwy + hi.x*wy)*cwx[0] + (lo.y*cwy + hi.y*wy)*wx[0];
        va[1] = (lo.z*cwy + hi.z*wy)*cwx[1] + (lo.w*cwy + hi.w*wy)*wx[1];
        va[2] = (loh.x*cwy + hih.x*wy)*cwx[2] + (loh.y*cwy + hih.y*wy)*wx[2];
        va[3] = (loh.z*cwy + hih.z*wy)*cwx[3] + (loh.w*cwy + hih.w*wy)*wx[3];
        vb[0] = (ql.x*cwy + qh.x*wy)*cwx[0] + (ql.y*cwy + qh.y*wy)*wx[0];
        vb[1] = (ql.z*cwy + qh.z*wy)*cwx[1] + (ql.w*cwy + qh.w*wy)*wx[1];
        vb[2] = (qlh.x*cwy + qhh.x*wy)*cwx[2] + (qlh.y*cwy + qhh.y*wy)*wx[2];
        vb[3] = (qlh.z*cwy + qhh.z*wy)*cwx[3] + (qlh.w*cwy + qhh.w*wy)*wx[3];
        acc0 += va[0] + va[1] + va[2] + va[3];
        acc1 += vb[0] + vb[1] + vb[2] + vb[3];

        unsigned pr = (pred >> (4 * r)) & 0xF;
        u64 b0 = __ballot((pr & 1) != 0);
        u64 b1 = __ballot((pr & 2) != 0);
        u64 b2 = __ballot((pr & 4) != 0);
        u64 b3 = __ballot((pr & 8) != 0);
        u64 ltm = (1ull << lane) - 1ull;
        int pre = __popcll(b0 & ltm) + __popcll(b1 & ltm) +
                  __popcll(b2 & ltm) + __popcll(b3 & ltm);
        int rbase = base0 + rc + pre;
        int own = 0;
        #pragma unroll
        for (int j = 0; j < 4; ++j) {
            if (pr & (1u << j)) {
                int row = rbase + own;
                own++;
                int x = 4 * lane + j;
                float cy = (float)y + 0.5f, cx = (float)x + 0.5f;
                write_row(out, N, row, cy, cx, va[j], vb[j], 0.5f, 1.0f,
                          (float)bimg, (float)prow,
                          (float)((bimg << 16) + (y << 8) + x));
            }
        }
        rc += __popcll(b0) + __popcll(b1) + __popcll(b2) + __popcll(b3);
    }

    part[gh * 64 + lane] = make_float2(acc0, acc1);
}

// ---------------------------------------------------------------------------
// finish1: combine the two half partials per level-1 cell, write L1 rows.
// ---------------------------------------------------------------------------
__global__ __launch_bounds__(256) void finish1_kernel(const float2* __restrict__ part,
                                                      const u64* __restrict__ mask1,
                                                      const int* __restrict__ offs1,
                                                      const int* __restrict__ totals,
                                                      float* __restrict__ out, int N) {
    int tid = threadIdx.x, lane = tid & 63;
    int g = blockIdx.x * 4 + (tid >> 6);             // 0..4095
    u64 m1 = mask1[g];
    if (m1 == 0ull) return;
    float2 p0 = part[(2 * g) * 64 + lane];
    float2 p1 = part[(2 * g + 1) * 64 + lane];
    if (!((m1 >> lane) & 1ull)) return;
    int prow = totals[0] + offs1[g] + __popcll(m1 & ((1ull << lane) - 1ull));
    float v0 = (p0.x + p1.x) * (1.0f / 16.0f);
    float v1 = (p0.y + p1.y) * (1.0f / 16.0f);
    int bimg = g >> 6, R = g & 63;
    float cy = ((float)R + 0.5f) * 4.0f, cx = ((float)lane + 0.5f) * 4.0f;
    write_row(out, N, prow, cy, cx, v0, v1, 2.0f, 4.0f, (float)bimg,
              (float)prow, (float)(OFFSET1 + g * 64 + lane));
}

extern "C" void kernel_launch(void* const* d_in, const int* in_sizes, int n_in,
                              void* d_out, int out_size, void* d_ws, size_t ws_size,
                              hipStream_t stream) {
    const float* E = (const float*)d_in[0];   // b_edges (64,1,512,512)
    const float* S = (const float*)d_in[1];   // sobel   (64,2,512,512)
    float* out = (float*)d_out;
    int N = out_size / 12;                    // 8 outputs = 12 floats/row

    // workspace layout (byte offsets); ~4.8 MB total, all written before read
    char* ws = (char*)d_ws;
    int* counts0 = (int*)(ws + 0);            // 4096 ints
    int* offs0   = (int*)(ws + 16384);        // 4096
    int* counts1 = (int*)(ws + 32768);        // 4096
    int* offs1   = (int*)(ws + 49152);        // 4096
    int* totals  = (int*)(ws + 65536);        // 2
    u64* mask1   = (u64*)(ws + 65600);        // 4096 u64 = 32 KB
    unsigned short* pred16 = (unsigned short*)(ws + 98368);  // 512 KB
    float2* part = (float2*)(ws + 622656);    // 8192*64 float2 = 4 MB

    prepE_kernel<<<1024, 256, 0, stream>>>(E, pred16, mask1, counts0, counts1);
    scan_kernel<<<1, 1024, 0, stream>>>(counts0, offs0, counts1, offs1, totals);
    prepSa_kernel<<<2048, 256, 0, stream>>>(S, pred16, mask1, offs0, offs1,
                                            totals, part, out, N);
    finish1_kernel<<<1024, 256, 0, stream>>>(part, mask1, offs1, totals, out, N);
}